// Round 1
// baseline (464.258 us; speedup 1.0000x reference)
//
#include <hip/hip_runtime.h>
#include <stdint.h>
#include <stddef.h>

#define TSEQ   2048
#define HDIM   512
#define NHEADS 8
#define HEADD  64
#define NVOCAB 32000
#define NROWS  4096   // B*T

typedef unsigned short ushort_t;
typedef __bf16 bf16x8 __attribute__((ext_vector_type(8)));
typedef float  f32x4  __attribute__((ext_vector_type(4)));
typedef unsigned short us8 __attribute__((ext_vector_type(8)));
typedef unsigned short us4 __attribute__((ext_vector_type(4)));
typedef unsigned short us2 __attribute__((ext_vector_type(2)));

__device__ __forceinline__ ushort_t f2bf(float f){
  union { float f; unsigned int u; } v; v.f = f;
  unsigned int u = v.u;
  u += 0x7FFFu + ((u >> 16) & 1u);   // RNE
  return (ushort_t)(u >> 16);
}

__device__ __forceinline__ void gload_lds16(const ushort_t* g, ushort_t* l){
  __builtin_amdgcn_global_load_lds(
      (const __attribute__((address_space(1))) void*)g,
      (__attribute__((address_space(3))) void*)l, 16, 0, 0);
}

// ---------------- f32 -> bf16 convert ----------------
__global__ void cvt_bf16_kernel(const float* __restrict__ src,
                                ushort_t* __restrict__ dst, int n4){
  int stride = gridDim.x * blockDim.x;
  for (int i = blockIdx.x * blockDim.x + threadIdx.x; i < n4; i += stride){
    float4 f = ((const float4*)src)[i];
    us4 o;
    o[0] = f2bf(f.x); o[1] = f2bf(f.y); o[2] = f2bf(f.z); o[3] = f2bf(f.w);
    ((us4*)dst)[i] = o;
  }
}

// ---------------- embedding: x0 = tok[ix] + pos ----------------
__global__ void embed_kernel(const int* __restrict__ ixs, const float* __restrict__ tok,
                             const float* __restrict__ pos, ushort_t* __restrict__ x0){
  const int r = blockIdx.x;            // 0..4095 (b*T + t)
  const int t = r & (TSEQ - 1);
  const int ix = ixs[r];
  const int j = threadIdx.x;           // 0..255, 2 floats each
  const float2 a = ((const float2*)(tok + (size_t)ix * HDIM))[j];
  const float2 p = ((const float2*)(pos + (size_t)t * HDIM))[j];
  us2 o; o[0] = f2bf(a.x + p.x); o[1] = f2bf(a.y + p.y);
  *(us2*)(x0 + (size_t)r * HDIM + j * 2) = o;
}

// ---------------- GEMM: C[M,N] = A[M,K] @ W[N,K]^T (+bias)(+relu) ----------------
// m97 structure: 128x128 tile, BK=64, 4 waves (2x2 of 64x64), 16x16x32 bf16 MFMA
template<int HAS_BIAS, int RELU, int OUT_F32>
__global__ __launch_bounds__(256) void gemm_bt_kernel(
    const ushort_t* __restrict__ A, const ushort_t* __restrict__ W,
    const float* __restrict__ bias, void* __restrict__ outp,
    int M, int N, int K)
{
  __shared__ ushort_t As[128 * 64];
  __shared__ ushort_t Bs[128 * 64];
  const int tid  = threadIdx.x;
  const int wave = tid >> 6;
  const int lane = tid & 63;
  const int lr   = lane & 15;
  const int lg   = lane >> 4;
  const int nbx  = N >> 7;
  const int bx   = blockIdx.x % nbx;
  const int by   = blockIdx.x / nbx;
  const int row0 = by << 7;
  const int col0 = bx << 7;
  const int wr   = wave >> 1, wc = wave & 1;

  f32x4 acc[4][4];
#pragma unroll
  for (int m = 0; m < 4; m++)
#pragma unroll
    for (int n = 0; n < 4; n++) acc[m][n] = (f32x4){0.f, 0.f, 0.f, 0.f};

  const int e    = tid * 8;        // element offset within a 4096-elem pass
  const int srow = e >> 6;         // 0..31
  const int scol = e & 63;
  const ushort_t* gA = A + (size_t)(row0 + srow) * K + scol;
  const ushort_t* gB = W + (size_t)(col0 + srow) * K + scol;
  const int ldsbase = wave * 512;  // elements; wave-uniform

  for (int kt = 0; kt < K; kt += 64){
#pragma unroll
    for (int p = 0; p < 4; p++){
      gload_lds16(gA + (size_t)(p * 32) * K + kt, &As[p * 2048 + ldsbase]);
      gload_lds16(gB + (size_t)(p * 32) * K + kt, &Bs[p * 2048 + ldsbase]);
    }
    __syncthreads();
#pragma unroll
    for (int kk = 0; kk < 64; kk += 32){
      bf16x8 af[4], bfr[4];
#pragma unroll
      for (int m = 0; m < 4; m++)
        af[m] = __builtin_bit_cast(bf16x8,
            *(const us8*)&As[(wr * 64 + m * 16 + lr) * 64 + kk + lg * 8]);
#pragma unroll
      for (int n = 0; n < 4; n++)
        bfr[n] = __builtin_bit_cast(bf16x8,
            *(const us8*)&Bs[(wc * 64 + n * 16 + lr) * 64 + kk + lg * 8]);
#pragma unroll
      for (int m = 0; m < 4; m++)
#pragma unroll
        for (int n = 0; n < 4; n++)
          acc[m][n] = __builtin_amdgcn_mfma_f32_16x16x32_bf16(af[m], bfr[n], acc[m][n], 0, 0, 0);
    }
    __syncthreads();
  }

#pragma unroll
  for (int n = 0; n < 4; n++){
    const int col = col0 + wc * 64 + n * 16 + lr;
    float bv = 0.f;
    if (HAS_BIAS) bv = bias[col];
#pragma unroll
    for (int m = 0; m < 4; m++){
      const int rowb = row0 + wr * 64 + m * 16 + lg * 4;
#pragma unroll
      for (int r = 0; r < 4; r++){
        float vv = acc[m][n][r] + bv;
        if (RELU) vv = fmaxf(vv, 0.f);
        const size_t o = (size_t)(rowb + r) * N + col;
        if (OUT_F32) ((float*)outp)[o] = vv;
        else         ((ushort_t*)outp)[o] = f2bf(vv);
      }
    }
  }
}

// ---------------- fused causal flash attention ----------------
// block = 4 waves; wave w owns 16 q-rows of a 64-row q-tile. K/V tiles of 64.
__global__ __launch_bounds__(256) void attn_kernel(
    const ushort_t* __restrict__ qkv, ushort_t* __restrict__ y)
{
  __shared__ ushort_t Ks[64 * 64];
  __shared__ ushort_t Vt[64 * 64];     // transposed: [d][key]
  __shared__ ushort_t Ps[4][16 * 64];
  const int qt   = blockIdx.x;         // 0..31
  const int hb   = blockIdx.y;         // 0..15
  const int b    = hb >> 3;
  const int h    = hb & 7;
  const int tid  = threadIdx.x;
  const int wave = tid >> 6, lane = tid & 63;
  const int lr   = lane & 15, lg = lane >> 4;
  const int ld   = 3 * HDIM;           // qkv row stride = 1536
  const size_t rowbase = (size_t)b * TSEQ;
  const ushort_t* kb = qkv + HDIM;
  const ushort_t* vb = qkv + 2 * HDIM;

  const int qrow = qt * 64 + wave * 16 + lr;
  const ushort_t* qp = qkv + (rowbase + qrow) * ld + h * HEADD;
  bf16x8 qf[2];
  qf[0] = __builtin_bit_cast(bf16x8, *(const us8*)&qp[lg * 8]);
  qf[1] = __builtin_bit_cast(bf16x8, *(const us8*)&qp[32 + lg * 8]);

  float m_run[4], l_run[4];
  f32x4 acc_o[4];
#pragma unroll
  for (int i = 0; i < 4; i++){ m_run[i] = -1e30f; l_run[i] = 0.f; acc_o[i] = (f32x4){0,0,0,0}; }

  const int e    = tid * 8;
  const int srow = e >> 6;
  const int scol = e & 63;
  const float scale = 0.04419417382415922f;   // 1/sqrt(512) (full H per reference!)

  for (int kt = 0; kt <= qt; ++kt){
    const ushort_t* gK = kb + (rowbase + kt * 64 + srow) * ld + h * HEADD + scol;
    gload_lds16(gK,                     &Ks[wave * 512]);
    gload_lds16(gK + (size_t)32 * ld,   &Ks[2048 + wave * 512]);
    const ushort_t* gV = vb + (rowbase + kt * 64 + srow) * ld + h * HEADD + scol;
    us8 v0 = *(const us8*)gV;
    us8 v1 = *(const us8*)(gV + (size_t)32 * ld);
#pragma unroll
    for (int j = 0; j < 8; j++){
      Vt[(scol + j) * 64 + srow]      = v0[j];
      Vt[(scol + j) * 64 + srow + 32] = v1[j];
    }
    __syncthreads();

    // S = Q @ K^T  (C layout: col=key=lane&15 within frag n, row=q=lg*4+r)
    f32x4 s[4];
#pragma unroll
    for (int n = 0; n < 4; n++){
      s[n] = (f32x4){0, 0, 0, 0};
#pragma unroll
      for (int ks = 0; ks < 2; ks++){
        bf16x8 kf = __builtin_bit_cast(bf16x8,
            *(const us8*)&Ks[(n * 16 + lr) * 64 + ks * 32 + lg * 8]);
        s[n] = __builtin_amdgcn_mfma_f32_16x16x32_bf16(qf[ks], kf, s[n], 0, 0, 0);
      }
    }

    float sv[4][4];
    float tmax[4] = {-1e30f, -1e30f, -1e30f, -1e30f};
    const bool diag = (kt == qt);
#pragma unroll
    for (int n = 0; n < 4; n++)
#pragma unroll
      for (int r = 0; r < 4; r++){
        float x = s[n][r] * scale;
        if (diag && (n * 16 + lr) > (wave * 16 + lg * 4 + r)) x = -1e30f;
        sv[n][r] = x;
        tmax[r] = fmaxf(tmax[r], x);
      }
#pragma unroll
    for (int off = 1; off < 16; off <<= 1)
#pragma unroll
      for (int r = 0; r < 4; r++) tmax[r] = fmaxf(tmax[r], __shfl_xor(tmax[r], off));

    float alpha[4], psum[4];
#pragma unroll
    for (int r = 0; r < 4; r++){
      float mn = fmaxf(m_run[r], tmax[r]);
      alpha[r] = __expf(m_run[r] - mn);
      m_run[r] = mn;
      psum[r] = 0.f;
    }
    float p[4][4];
#pragma unroll
    for (int n = 0; n < 4; n++)
#pragma unroll
      for (int r = 0; r < 4; r++){ p[n][r] = __expf(sv[n][r] - m_run[r]); psum[r] += p[n][r]; }
#pragma unroll
    for (int off = 1; off < 16; off <<= 1)
#pragma unroll
      for (int r = 0; r < 4; r++) psum[r] += __shfl_xor(psum[r], off);
#pragma unroll
    for (int r = 0; r < 4; r++) l_run[r] = l_run[r] * alpha[r] + psum[r];
#pragma unroll
    for (int nd = 0; nd < 4; nd++)
#pragma unroll
      for (int r = 0; r < 4; r++) acc_o[nd][r] *= alpha[r];

    // P (C-layout) -> LDS -> A-layout fragments
#pragma unroll
    for (int n = 0; n < 4; n++)
#pragma unroll
      for (int r = 0; r < 4; r++)
        Ps[wave][(lg * 4 + r) * 64 + n * 16 + lr] = f2bf(p[n][r]);
    asm volatile("s_waitcnt lgkmcnt(0)" ::: "memory");
    bf16x8 pa[2];
    pa[0] = __builtin_bit_cast(bf16x8, *(const us8*)&Ps[wave][lr * 64 + lg * 8]);
    pa[1] = __builtin_bit_cast(bf16x8, *(const us8*)&Ps[wave][lr * 64 + 32 + lg * 8]);
#pragma unroll
    for (int nd = 0; nd < 4; nd++)
#pragma unroll
      for (int ks = 0; ks < 2; ks++){
        bf16x8 vf = __builtin_bit_cast(bf16x8,
            *(const us8*)&Vt[(nd * 16 + lr) * 64 + ks * 32 + lg * 8]);
        acc_o[nd] = __builtin_amdgcn_mfma_f32_16x16x32_bf16(pa[ks], vf, acc_o[nd], 0, 0, 0);
      }
    __syncthreads();
  }

  float inv[4];
#pragma unroll
  for (int r = 0; r < 4; r++) inv[r] = 1.f / l_run[r];
#pragma unroll
  for (int nd = 0; nd < 4; nd++)
#pragma unroll
    for (int r = 0; r < 4; r++){
      const int row_t = qt * 64 + wave * 16 + lg * 4 + r;
      y[(rowbase + row_t) * HDIM + h * HEADD + nd * 16 + lr] = f2bf(acc_o[nd][r] * inv[r]);
    }
}

// ---------------- launch ----------------
extern "C" void kernel_launch(void* const* d_in, const int* in_sizes, int n_in,
                              void* d_out, int out_size, void* d_ws, size_t ws_size,
                              hipStream_t stream)
{
  const int*   ixs  = (const int*)  d_in[0];
  const float* tok  = (const float*)d_in[1];
  const float* pos  = (const float*)d_in[2];
  const float* Wprj = (const float*)d_in[3];
  const float* Wq   = (const float*)d_in[4];
  const float* bq_  = (const float*)d_in[5];
  const float* Wk   = (const float*)d_in[6];
  const float* bk_  = (const float*)d_in[7];
  const float* Wv   = (const float*)d_in[8];
  const float* bv_  = (const float*)d_in[9];
  const float* W1   = (const float*)d_in[10];
  const float* b1_  = (const float*)d_in[11];
  const float* W2   = (const float*)d_in[12];
  const float* b2_  = (const float*)d_in[13];
  float* out = (float*)d_out;

  ushort_t* ws    = (ushort_t*)d_ws;
  ushort_t* x0    = ws;                          // 4096*512
  ushort_t* x1    = x0    + 2097152;
  ushort_t* qkv   = x1    + 2097152;             // 4096*1536
  ushort_t* yb    = qkv   + 6291456;
  ushort_t* h1b   = yb    + 2097152;
  ushort_t* wprjb = h1b   + 2097152;             // 512*512
  ushort_t* wqkvb = wprjb + 262144;              // 3*512*512
  ushort_t* w1b   = wqkvb + 786432;
  ushort_t* w2b   = w1b   + 262144;              // 32000*512
  float*    bqkv  = (float*)(w2b + 16384000);    // 1536 f32

  auto cvtN = [&](const float* s, ushort_t* d, int n){
    int n4 = n >> 2;
    int blocks = (n4 + 255) >> 8; if (blocks > 2048) blocks = 2048;
    cvt_bf16_kernel<<<blocks, 256, 0, stream>>>(s, d, n4);
  };
  cvtN(Wprj, wprjb, 262144);
  cvtN(Wq,   wqkvb,          262144);
  cvtN(Wk,   wqkvb + 262144, 262144);
  cvtN(Wv,   wqkvb + 524288, 262144);
  cvtN(W1,   w1b, 262144);
  cvtN(W2,   w2b, 16384000);
  hipMemcpyAsync(bqkv,        bq_, 512 * 4, hipMemcpyDeviceToDevice, stream);
  hipMemcpyAsync(bqkv + 512,  bk_, 512 * 4, hipMemcpyDeviceToDevice, stream);
  hipMemcpyAsync(bqkv + 1024, bv_, 512 * 4, hipMemcpyDeviceToDevice, stream);

  embed_kernel<<<NROWS, 256, 0, stream>>>(ixs, tok, pos, x0);

  // x1 = x0 @ Wprj^T
  gemm_bt_kernel<0,0,0><<<32 * 4,   256, 0, stream>>>(x0,  wprjb, nullptr, x1,  NROWS, 512,   512);
  // qkv (fused q|k|v, N=1536)
  gemm_bt_kernel<1,0,0><<<32 * 12,  256, 0, stream>>>(x1,  wqkvb, bqkv,    qkv, NROWS, 1536,  512);
  // attention
  attn_kernel<<<dim3(32, 16), 256, 0, stream>>>(qkv, yb);
  // h1 = relu(y @ W1^T + b1)
  gemm_bt_kernel<1,1,0><<<32 * 4,   256, 0, stream>>>(yb,  w1b,   b1_,     h1b, NROWS, 512,   512);
  // out = relu(h1 @ W2^T + b2)  -> f32
  gemm_bt_kernel<1,1,1><<<32 * 250, 256, 0, stream>>>(h1b, w2b,   b2_,     out, NROWS, NVOCAB, 512);
}